// Round 8
// baseline (232.352 us; speedup 1.0000x reference)
//
#include <hip/hip_runtime.h>
#include <hip/hip_bf16.h>

// Problem constants
#define BATCH   256
#define NP      196
#define HIDDEN  1024
#define ATT     512
#define M_TOTAL (BATCH * NP)   // 50176 rows
#define BM 256
#define BN 128
#define BK 64
#define NB_TILES (ATT / BN)       // 4
#define MT_TILES (M_TOTAL / BM)   // 196
#define KTILES   (HIDDEN / BK)    // 16

typedef __attribute__((ext_vector_type(8))) short bf16x8v;  // 8 bf16 = 4 VGPR
typedef __attribute__((ext_vector_type(4))) float f32x4;

// f32 -> bf16 RNE (used only in K0 prep, cold path)
__device__ inline unsigned short f2bf(float x) {
    unsigned int u = __float_as_uint(x);
    u += 0x7fffu + ((u >> 16) & 1u);
    return (unsigned short)(u >> 16);
}

// packed f32 pair -> 2x bf16 in one uint via v_cvt_pk_bf16_f32
__device__ __forceinline__ unsigned int pk2bf(float lo, float hi) {
    unsigned int r;
    asm("v_cvt_pk_bf16_f32 %0, %1, %2" : "=v"(r) : "v"(lo), "v"(hi));
    return r;
}

__device__ inline float fast_tanh(float x) {
    float e = __expf(2.0f * x);
    return 1.0f - 2.0f / (e + 1.0f);
}

// async global->LDS, 16 bytes per lane (per-wave base from each wave's lane 0).
__device__ __forceinline__ void glds16(const void* gsrc, void* ldst) {
    __builtin_amdgcn_global_load_lds(
        (const __attribute__((address_space(1))) unsigned int*)gsrc,
        (__attribute__((address_space(3))) unsigned int*)ldst,
        16, 0, 0);
}

// ---------------------------------------------------------------------------
// K0: W_cnn (f32 [1024][512]) -> bf16 tiled+XOR-swizzled for K2's B LDS image.
// Wt[nb 4][kt 16][16KB image]; image byte = col*128 + cp*16 (col 0..127 local).
// Slot cp holds k-chunk c = cp ^ (col&7), k = kt*64 + c*8 + j (8 consecutive).
// glds copies the image linearly; the LDS read applies the same XOR (rule #21).
// ---------------------------------------------------------------------------
__global__ void k0_arrange(const float* __restrict__ Wc, unsigned short* __restrict__ Wt) {
    int g = blockIdx.x * 256 + threadIdx.x;   // 65536 slots of 8 bf16
    int nb  = g >> 14;
    int kt  = (g >> 10) & 15;
    int col = (g >> 3) & 127;
    int cp  = g & 7;
    int c   = cp ^ (col & 7);
    int kb  = kt * 64 + c * 8;
    int colg = nb * 128 + col;
    unsigned short v[8];
#pragma unroll
    for (int j = 0; j < 8; ++j) v[j] = f2bf(Wc[(size_t)(kb + j) * ATT + colg]);
    uint4 pk;
    pk.x = (unsigned int)v[0] | ((unsigned int)v[1] << 16);
    pk.y = (unsigned int)v[2] | ((unsigned int)v[3] << 16);
    pk.z = (unsigned int)v[4] | ((unsigned int)v[5] << 16);
    pk.w = (unsigned int)v[6] | ((unsigned int)v[7] << 16);
    *(uint4*)(Wt + (size_t)g * 8) = pk;
}

// ---------------------------------------------------------------------------
// K1: dec_out = decoder_out @ W_dec ; stw = st @ W_sen   (f32)
// ---------------------------------------------------------------------------
__global__ void k1_small(const float* __restrict__ dec_in, const float* __restrict__ st,
                         const float* __restrict__ Wdec,  const float* __restrict__ Wsen,
                         float* __restrict__ dec_out, float* __restrict__ stw) {
    const float* X = blockIdx.z ? st   : dec_in;
    const float* W = blockIdx.z ? Wsen : Wdec;
    float*       O = blockIdx.z ? stw  : dec_out;
    int ci = threadIdx.x & 31;
    int c0 = blockIdx.x * 128 + ci * 4;
    int b  = blockIdx.y * 8 + (threadIdx.x >> 5);
    const float* x = X + (size_t)b * HIDDEN;
    float4 acc = {0.f, 0.f, 0.f, 0.f};
    for (int k = 0; k < HIDDEN; k += 4) {
#pragma unroll
        for (int kk = 0; kk < 4; ++kk) {
            float4 w = *(const float4*)(W + (size_t)(k + kk) * ATT + c0);
            float a = x[k + kk];
            acc.x += a * w.x; acc.y += a * w.y; acc.z += a * w.z; acc.w += a * w.w;
        }
    }
    *(float4*)(O + (size_t)b * ATT + c0) = acc;
}

// ---------------------------------------------------------------------------
// K2: fused  zt_part[nb][r] = sum_{cols of nb} tanh((A@Wc)[r,a]+dec)*Watt[a]
// m201-style phase structure: 256x128 tile, BK=64, 8 waves (2x4), wave out
// 128x32 (acc[8][2]). Per K-tile TWO phases, each a barrier-PAIR around a
// 16-MFMA cluster with lgkmcnt(0)+sched_barrier (rule #18) + setprio (T5).
// P0: ds_read kk0 + issue A-loads(t+1) + B-glds(t+1).
// P1: ds_read kk1 + cvt/ds_write A(t+1) (compiler's counted vmcnt keeps the
//     glds in flight) + MFMA + vmcnt(0) (only the 2 glds remain) + barrier.
// All LDS images XOR-swizzled (chunk ^ (row&7)); inverse baked into Wt,
// applied on both A write and all reads -> conflict-free. 1 block/CU: the
// barrier-pair wave stagger hides staging (m201 mechanism, not co-residency).
// ---------------------------------------------------------------------------
__global__ void __launch_bounds__(512, 1)
k2_fused_gemm(const float* __restrict__ A, const unsigned short* __restrict__ Wt,
              const float* __restrict__ dec, const float* __restrict__ Watt,
              float* __restrict__ ztp) {
    __shared__ __align__(16) char ldsA[2][32768];   // 256 rows x 128 B (bf16)
    __shared__ __align__(16) char ldsB[2][16384];   // 128 cols x 128 B (bf16)
    __shared__ float zred[1024];

    const int tid = threadIdx.x;
    const int w  = tid >> 6;
    const int l  = tid & 63;
    const int lg = l >> 4, ll = l & 15;
    const int wr = w >> 2, wc = w & 3;       // 2 row-waves x 4 col-waves

    // XCD-bijective swizzle: 784 = 8 XCDs x 98; the 4 nb-blocks of each mt
    // are adjacent within an XCD chunk -> A strip + Wt L2 reuse.
    const int bid = (int)blockIdx.x;
    const int swz = (bid & 7) * 98 + (bid >> 3);
    const int mt = swz >> 2, nb = swz & 3;
    const int r0 = mt * BM;
    const int c0 = nb * BN;

    f32x4 acc[8][2];
#pragma unroll
    for (int m = 0; m < 8; ++m)
#pragma unroll
        for (int n = 0; n < 2; ++n) acc[m][n] = (f32x4){0.f, 0.f, 0.f, 0.f};

    // A staging: load j (0..7): row = (tid>>4)+32j, k-quad = (tid&15)*4 within
    // the 64-wide K-tile (wave reads 4 rows x 256 B contiguous per instr).
    const float* asrc = A + (size_t)(r0 + (tid >> 4)) * HIDDEN + (tid & 15) * 4;
    // ds_write_b64: byte = row*128 + ((c ^ (row&7))<<4) + h*8,
    // c = (tid>>1)&7, h = tid&1, row&7 = (tid>>4)&7 (j-invariant).
    const int aw_off = ((tid >> 4) * 128)
                     + (((((tid >> 1) & 7) ^ ((tid >> 4) & 7))) << 4)
                     + ((tid & 1) << 3);
    // B: linear 16 KB image per (nb, kt); 2 glds per K-tile.
    const char* bimg = (const char*)Wt + (size_t)nb * (KTILES * 16384);

#define AF_READS(Ab, kk)                                                        \
    _Pragma("unroll")                                                           \
    for (int m = 0; m < 8; ++m)                                                 \
        af[m] = *(const bf16x8v*)((Ab) + (wr * 128 + m * 16 + ll) * 128 +       \
                                  ((((kk) * 4 + lg) ^ (ll & 7)) << 4));
#define BF_READS(Bb, kk)                                                        \
    _Pragma("unroll")                                                           \
    for (int n = 0; n < 2; ++n)                                                 \
        bfr[n] = *(const bf16x8v*)((Bb) + (wc * 32 + n * 16 + ll) * 128 +       \
                                   ((((kk) * 4 + lg) ^ (ll & 7)) << 4));
#define MFMA16                                                                  \
    _Pragma("unroll")                                                           \
    for (int m = 0; m < 8; ++m)                                                 \
        _Pragma("unroll")                                                       \
        for (int n = 0; n < 2; ++n)                                             \
            acc[m][n] = __builtin_amdgcn_mfma_f32_16x16x32_bf16(                \
                af[m], bfr[n], acc[m][n], 0, 0, 0);
#define LGKM0_FENCE do {                                                        \
    asm volatile("s_waitcnt lgkmcnt(0)" ::: "memory");                          \
    __builtin_amdgcn_sched_barrier(0);                                          \
} while (0)
#define BAR __builtin_amdgcn_s_barrier()

    char* Acur = ldsA[0]; char* Anxt = ldsA[1];
    char* Bcur = ldsB[0]; char* Bnxt = ldsB[1];
    float4 av[8];

    // ---- Prologue: stage tile 0 ----
#pragma unroll
    for (int j = 0; j < 8; ++j)
        av[j] = *(const float4*)(asrc + (size_t)j * 32 * HIDDEN);
    glds16(bimg + 0    + tid * 16, Bcur + 0    + tid * 16);
    glds16(bimg + 8192 + tid * 16, Bcur + 8192 + tid * 16);
#pragma unroll
    for (int j = 0; j < 8; ++j) {    // compiler waits the A loads (vmcnt(2))
        uint2 u;
        u.x = pk2bf(av[j].x, av[j].y);
        u.y = pk2bf(av[j].z, av[j].w);
        *(uint2*)(Acur + j * 4096 + aw_off) = u;
    }
    asm volatile("s_waitcnt vmcnt(0)" ::: "memory");
    LGKM0_FENCE;
    BAR;

    // ---- Main loop: tiles 0..14, staging t+1 ----
    for (int t = 0; t < 15; ++t) {
        {   // phase 0 (kk = 0)
            bf16x8v af[8], bfr[2];
            AF_READS(Acur, 0); BF_READS(Bcur, 0);
            // stage t+1: A loads FIRST (so cvt's auto-wait keeps glds in flight)
#pragma unroll
            for (int j = 0; j < 8; ++j)
                av[j] = *(const float4*)(asrc + (size_t)j * 32 * HIDDEN + (t + 1) * 64);
            glds16(bimg + (size_t)(t + 1) * 16384 + 0    + tid * 16, Bnxt + 0    + tid * 16);
            glds16(bimg + (size_t)(t + 1) * 16384 + 8192 + tid * 16, Bnxt + 8192 + tid * 16);
            BAR;
            LGKM0_FENCE;
            __builtin_amdgcn_s_setprio(1);
            MFMA16;
            __builtin_amdgcn_s_setprio(0);
            BAR;
        }
        {   // phase 1 (kk = 1)
            bf16x8v af[8], bfr[2];
            AF_READS(Acur, 1); BF_READS(Bcur, 1);
            // cvt + ds_write A(t+1) (compiler emits counted vmcnt for av)
#pragma unroll
            for (int j = 0; j < 8; ++j) {
                uint2 u;
                u.x = pk2bf(av[j].x, av[j].y);
                u.y = pk2bf(av[j].z, av[j].w);
                *(uint2*)(Anxt + j * 4096 + aw_off) = u;
            }
            BAR;
            LGKM0_FENCE;
            __builtin_amdgcn_s_setprio(1);
            MFMA16;
            __builtin_amdgcn_s_setprio(0);
            asm volatile("s_waitcnt vmcnt(0)" ::: "memory");   // only the 2 glds remain
            BAR;
        }
        char* tA = Acur; Acur = Anxt; Anxt = tA;
        char* tB = Bcur; Bcur = Bnxt; Bnxt = tB;
    }

    // ---- Tail: tile 15, no staging ----
    {
        bf16x8v af[8], bfr[2];
        AF_READS(Acur, 0); BF_READS(Bcur, 0);
        LGKM0_FENCE;
        __builtin_amdgcn_s_setprio(1);
        MFMA16;
        __builtin_amdgcn_s_setprio(0);
    }
    {
        bf16x8v af[8], bfr[2];
        AF_READS(Acur, 1); BF_READS(Bcur, 1);
        LGKM0_FENCE;
        __builtin_amdgcn_s_setprio(1);
        MFMA16;
        __builtin_amdgcn_s_setprio(0);
    }

#undef AF_READS
#undef BF_READS
#undef MFMA16
#undef LGKM0_FENCE
#undef BAR

    // ---- Epilogue: tanh + dec add + Watt dot; reduce the wave's 32 cols/row.
    // C frag layout (m89-verified): row = lg*4 + j, col = ll.
    const int clocal = wc * 32 + ll;
    float watt[2];
#pragma unroll
    for (int n = 0; n < 2; ++n) watt[n] = Watt[c0 + clocal + n * 16];

#pragma unroll
    for (int m = 0; m < 8; ++m) {
#pragma unroll
        for (int j = 0; j < 4; ++j) {
            int rl = wr * 128 + m * 16 + lg * 4 + j;
            int rowg = r0 + rl;
            int b = rowg / NP;
            const float* db = dec + (size_t)b * ATT + c0;
            float s = 0.f;
#pragma unroll
            for (int n = 0; n < 2; ++n)
                s += fast_tanh(acc[m][n][j] + db[clocal + n * 16]) * watt[n];
            s += __shfl_xor(s, 1);
            s += __shfl_xor(s, 2);
            s += __shfl_xor(s, 4);
            s += __shfl_xor(s, 8);
            if (ll == 0) zred[rl * 4 + wc] = s;
        }
    }
    __syncthreads();
    if (tid < 256) {
        float t = zred[tid * 4] + zred[tid * 4 + 1] + zred[tid * 4 + 2] + zred[tid * 4 + 3];
        ztp[(size_t)nb * M_TOTAL + r0 + tid] = t;
    }
}

// ---------------------------------------------------------------------------
// K3: per-b: out = tanh(dec+stw)@Watt ; alpha = softmax(zt) ; beta.
// zt = sum of 4 N-block partials.
// ---------------------------------------------------------------------------
__global__ void k3_softmax(const float* __restrict__ dec, const float* __restrict__ stw,
                           const float* __restrict__ Watt, const float* __restrict__ ztp,
                           float* __restrict__ out, float* __restrict__ beta_ws) {
    int b = blockIdx.x;
    int t = threadIdx.x;
    __shared__ float red[256];

    float p = 0.f;
#pragma unroll
    for (int c = t; c < ATT; c += 256)
        p += fast_tanh(dec[(size_t)b * ATT + c] + stw[(size_t)b * ATT + c]) * Watt[c];
    red[t] = p;
    __syncthreads();
    for (int s = 128; s > 0; s >>= 1) { if (t < s) red[t] += red[t + s]; __syncthreads(); }
    float outv = red[0];
    __syncthreads();

    float z = -1e30f;
    if (t < NP) {
        z = ztp[b * NP + t] + ztp[M_TOTAL + b * NP + t]
          + ztp[2 * M_TOTAL + b * NP + t] + ztp[3 * M_TOTAL + b * NP + t];
    }
    red[t] = z;
    __syncthreads();
    for (int s = 128; s > 0; s >>= 1) { if (t < s) red[t] = fmaxf(red[t], red[t + s]); __syncthreads(); }
    float m1 = red[0];
    __syncthreads();

    float e = (t < NP) ? __expf(z - m1) : 0.f;
    red[t] = e;
    __syncthreads();
    for (int s = 128; s > 0; s >>= 1) { if (t < s) red[t] += red[t + s]; __syncthreads(); }
    float s1 = red[0];

    if (t < NP) out[b * NP + t] = e / s1;                       // alpha_t

    if (t == 0) {
        float m2 = fmaxf(m1, outv);
        float s2 = s1 * __expf(m1 - m2) + __expf(outv - m2);
        float beta = __expf(outv - m2) / s2;
        out[M_TOTAL + b] = beta;                                 // beta_t
        beta_ws[b] = beta;
    }
}

// ---------------------------------------------------------------------------
// K4: ct partials. grid (4 p-quarters, 256 b), block 256 (thread = 4 h).
// ---------------------------------------------------------------------------
__global__ void k4_ct(const float* __restrict__ spatial, const float* __restrict__ alpha,
                      float* __restrict__ ctp) {
    int q = blockIdx.x;
    int b = blockIdx.y;
    int t = threadIdx.x;
    __shared__ float al[49];
    if (t < 49) al[t] = alpha[b * NP + q * 49 + t];
    __syncthreads();
    const float* sp = spatial + (size_t)b * NP * HIDDEN + (size_t)q * 49 * HIDDEN + t * 4;
    float4 acc = {0.f, 0.f, 0.f, 0.f};
#pragma unroll 7
    for (int p = 0; p < 49; ++p) {
        float4 v = *(const float4*)(sp + (size_t)p * HIDDEN);
        float a = al[p];
        acc.x += a * v.x; acc.y += a * v.y; acc.z += a * v.z; acc.w += a * v.w;
    }
    *(float4*)(ctp + ((size_t)q * BATCH + b) * HIDDEN + t * 4) = acc;
}

// ---------------------------------------------------------------------------
// K5: c_hat = beta*st + (1-beta)*ct  (sums the 4 ct partials)
// ---------------------------------------------------------------------------
__global__ void k5_chat(const float* __restrict__ st, const float* __restrict__ ctp,
                        const float* __restrict__ beta, float* __restrict__ chat) {
    int g = blockIdx.x * 256 + threadIdx.x;
    int b = g >> 8;
    int h0 = (g & 255) * 4;
    float be = beta[b];
    float4 s = *(const float4*)(st + (size_t)b * HIDDEN + h0);
    float4 c = {0.f, 0.f, 0.f, 0.f};
#pragma unroll
    for (int q = 0; q < 4; ++q) {
        float4 v = *(const float4*)(ctp + ((size_t)q * BATCH + b) * HIDDEN + h0);
        c.x += v.x; c.y += v.y; c.z += v.z; c.w += v.w;
    }
    float4 o;
    o.x = be * s.x + (1.f - be) * c.x;
    o.y = be * s.y + (1.f - be) * c.y;
    o.z = be * s.z + (1.f - be) * c.z;
    o.w = be * s.w + (1.f - be) * c.w;
    *(float4*)(chat + (size_t)b * HIDDEN + h0) = o;
}

// ---------------------------------------------------------------------------
extern "C" void kernel_launch(void* const* d_in, const int* in_sizes, int n_in,
                              void* d_out, int out_size, void* d_ws, size_t ws_size,
                              hipStream_t stream) {
    const float* spatial = (const float*)d_in[0];   // (256,196,1024)
    const float* decoder = (const float*)d_in[1];   // (256,1024)
    const float* st      = (const float*)d_in[2];   // (256,1024)
    const float* Wcnn    = (const float*)d_in[3];   // (1024,512)
    const float* Wdec    = (const float*)d_in[4];   // (1024,512)
    const float* Wsen    = (const float*)d_in[5];   // (1024,512)
    const float* Watt    = (const float*)d_in[6];   // (512,1)
    float* out = (float*)d_out;   // alpha[50176] | beta[256] | c_hat[262144]

    char* ws = (char*)d_ws;
    unsigned short* Wt = (unsigned short*)(ws + 0);   // 1 MB tiled+swizzled bf16 W_cnn
    float* ztp  = (float*)(ws + 1048576);             // 4 x 50176 partials (802816 B)
    float* dec  = (float*)(ws + 1851392);             // 256x512
    float* stw  = (float*)(ws + 2375680);             // 256x512
    float* beta = (float*)(ws + 2899968);             // 256
    float* ctp  = (float*)(ws + 2901504);             // 4x256x1024 partials (4 MB)

    k0_arrange<<<256, 256, 0, stream>>>(Wcnn, Wt);
    k1_small<<<dim3(4, 32, 2), 256, 0, stream>>>(decoder, st, Wdec, Wsen, dec, stw);
    k2_fused_gemm<<<MT_TILES * NB_TILES, 512, 0, stream>>>(spatial, Wt, dec, Watt, ztp);
    k3_softmax<<<256, 256, 0, stream>>>(dec, stw, Watt, ztp, out, beta);
    k4_ct<<<dim3(4, 256), 256, 0, stream>>>(spatial, out, ctp);
    k5_chat<<<256, 256, 0, stream>>>(st, ctp, beta, out + M_TOTAL + BATCH);
}